// Round 12
// baseline (130.425 us; speedup 1.0000x reference)
//
#include <hip/hip_runtime.h>
#include <hip/hip_bf16.h>
#include <math.h>

// Problem constants (fixed by setup_inputs)
#define B_ 16
#define L_ 1024
#define E_ 512
#define H_ 8
#define DH 64

typedef unsigned short u16;
typedef __attribute__((ext_vector_type(8))) short bf16x8;
typedef __attribute__((ext_vector_type(8))) unsigned short u16x8;
typedef __attribute__((ext_vector_type(4))) float f32x4;
typedef __attribute__((ext_vector_type(16))) float f32x16;

#define MFMA16(A, B, C) __builtin_amdgcn_mfma_f32_16x16x32_bf16(A, B, C, 0, 0, 0)
#define MFMA32(A, B, C) __builtin_amdgcn_mfma_f32_32x32x16_bf16(A, B, C, 0, 0, 0)

#if __has_builtin(__builtin_amdgcn_exp2f)
#define EXP2(x) __builtin_amdgcn_exp2f(x)
#else
#define EXP2(x) exp2f(x)
#endif

__device__ inline u16 f2b(float x) {
    __hip_bfloat16 h = __float2bfloat16(x);
    u16 u; __builtin_memcpy(&u, &h, 2); return u;
}

// hardware packed f32->bf16 (RNE), lo = a, hi = b
__device__ inline unsigned int cvt_pk_bf16(float a, float b) {
    unsigned int r;
    asm("v_cvt_pk_bf16_f32 %0, %1, %2" : "=v"(r) : "v"(a), "v"(b));
    return r;
}

// ---------------- QueryScaler precompute ----------------
// Folds: R_softplus0 * softplus(s) * (1/sqrt(Dh)) * log2(e)  -> exp2 softmax
__global__ void qscale_kernel(const float* __restrict__ qs_scale,
                              float* __restrict__ qscale) {
    int d = threadIdx.x;
    if (d < DH) {
        float x = qs_scale[d];
        float sp = (x > 20.f) ? x : log1pf(expf(x));
        qscale[d] = 1.442695041f * sp * 0.125f * 1.442695041f;
    }
}

// ---------------- fp32 -> bf16 conversion (x, w_in, w_out) ----------------
__global__ __launch_bounds__(256) void cvt_bf16(
    const float* __restrict__ x, const float* __restrict__ wi,
    const float* __restrict__ wo, u16* __restrict__ xb,
    u16* __restrict__ wib, u16* __restrict__ wob)
{
    int i = blockIdx.x * 256 + threadIdx.x;
    const float* src; u16* dst; size_t off;
    if (i < 1048576)      { src = x;  dst = xb;  off = (size_t)i * 8; }
    else if (i < 1146880) { src = wi; dst = wib; off = (size_t)(i - 1048576) * 8; }
    else                  { src = wo; dst = wob; off = (size_t)(i - 1146880) * 8; }
    float4 a = *(const float4*)(src + off);
    float4 b = *(const float4*)(src + off + 4);
    u16x8 r;
    r[0] = f2b(a.x); r[1] = f2b(a.y); r[2] = f2b(a.z); r[3] = f2b(a.w);
    r[4] = f2b(b.x); r[5] = f2b(b.y); r[6] = f2b(b.z); r[7] = f2b(b.w);
    *(u16x8*)(dst + off) = r;
}

// ---------------- bf16 MFMA GEMM: C = A(M,512) @ W(N,512)^T + bias --------
// m97 structure: 128x128 tile, BK=32, global_load_lds(16B) staging into
// double-buffered LDS, ONE barrier per K-step with explicit vmcnt(0)
// self-drain (round-9 race discipline). LDS dest linear (HW requirement);
// bank-conflict swizzle ch' = ch ^ (row&3) ^ ((row>>2)&3) applied as
// inverse-XOR on the GLOBAL source + same XOR on the ds_read (rule 21).
// Read side: row = wr*64+m*16+c -> swizzle = (c&3)^((c>>2)&3), m/wr-free.
// 4 waves (2x2), each wave 4x4 16x16x32 fragments (numerics identical to
// the round-11 reg-staged version).
template<int MODE>
__global__ __launch_bounds__(256) void gemm_bf16(
    const u16* __restrict__ A, const u16* __restrict__ W,
    const float* __restrict__ bias, const float* __restrict__ qscale,
    float* __restrict__ Dout, u16* __restrict__ Qb, u16* __restrict__ Kb,
    u16* __restrict__ Vtb)
{
    __shared__ u16 sA[2][4096];                // 2 x 8KB (512 slots x 16B)
    __shared__ u16 sB[2][4096];
    const int tid = threadIdx.x;
    const int m0 = blockIdx.x * 128;
    const int n0 = blockIdx.y * 128;
    const int wid = tid >> 6, lane = tid & 63;
    const int g = lane >> 4, c = lane & 15;
    const int wr = wid >> 1, wc = wid & 1;

    // staging map: thread covers slots tid and tid+256 of each matrix.
    // slot s: row = s>>2, chunk-slot = s&3 holds global chunk (s&3)^sw(row);
    // rows r and r+64 share sw -> one ch works for both halves.
    const int arow = tid >> 2;
    const int swg = (arow & 3) ^ ((arow >> 2) & 3);
    const int ch = (tid & 3) ^ swg;
    const u16* Asrc = A + (size_t)(m0 + arow) * 512 + ch * 8;
    const u16* Bsrc = W + (size_t)(n0 + arow) * 512 + ch * 8;

    auto stage = [&](int nbuf, int ks) {
        const int k0 = ks * 32;
        __builtin_amdgcn_global_load_lds(
            (const __attribute__((address_space(1))) unsigned int*)(Asrc + k0),
            (__attribute__((address_space(3))) unsigned int*)&sA[nbuf][wid * 512], 16, 0, 0);
        __builtin_amdgcn_global_load_lds(
            (const __attribute__((address_space(1))) unsigned int*)(Asrc + (size_t)64 * 512 + k0),
            (__attribute__((address_space(3))) unsigned int*)&sA[nbuf][2048 + wid * 512], 16, 0, 0);
        __builtin_amdgcn_global_load_lds(
            (const __attribute__((address_space(1))) unsigned int*)(Bsrc + k0),
            (__attribute__((address_space(3))) unsigned int*)&sB[nbuf][wid * 512], 16, 0, 0);
        __builtin_amdgcn_global_load_lds(
            (const __attribute__((address_space(1))) unsigned int*)(Bsrc + (size_t)64 * 512 + k0),
            (__attribute__((address_space(3))) unsigned int*)&sB[nbuf][2048 + wid * 512], 16, 0, 0);
    };

    f32x4 acc[4][4];
    #pragma unroll
    for (int m = 0; m < 4; m++)
        #pragma unroll
        for (int n = 0; n < 4; n++) acc[m][n] = (f32x4){0.f, 0.f, 0.f, 0.f};

    // read-side swizzle (row = ..*64 + m*16 + c -> depends only on c)
    const int swr = (c & 3) ^ ((c >> 2) & 3);
    const int chA = (g ^ swr) * 8;

    stage(0, 0);
    #pragma unroll 1
    for (int ks = 0; ks < 16; ks++) {
        const int cur = ks & 1;
        asm volatile("s_waitcnt vmcnt(0) lgkmcnt(0)" ::: "memory");
        __syncthreads();
        if (ks < 15) stage(cur ^ 1, ks + 1);   // overlaps with MFMA below

        bf16x8 af[4], bfr[4];
        #pragma unroll
        for (int m = 0; m < 4; m++)
            af[m] = *(const bf16x8*)&sA[cur][(wr * 64 + m * 16 + c) * 32 + chA];
        #pragma unroll
        for (int n = 0; n < 4; n++)
            bfr[n] = *(const bf16x8*)&sB[cur][(wc * 64 + n * 16 + c) * 32 + chA];
        #pragma unroll
        for (int m = 0; m < 4; m++)
            #pragma unroll
            for (int n = 0; n < 4; n++)
                acc[m][n] = MFMA16(af[m], bfr[n], acc[m][n]);
    }

    #pragma unroll
    for (int m = 0; m < 4; m++) {
        int rbase = m0 + wr * 64 + m * 16 + 4 * g;
        #pragma unroll
        for (int n = 0; n < 4; n++) {
            int f = n0 + wc * 64 + n * 16 + c;
            f32x4 v = acc[m][n];
            float bv = bias[f];
            if (MODE == 1) {
                #pragma unroll
                for (int reg = 0; reg < 4; reg++)
                    Dout[(size_t)(rbase + reg) * E_ + f] = v[reg] + bv;
            } else {
                int part = f >> 9, w = f & 511, h = w >> 6, d = w & 63;
                int bb = rbase >> 10;
                int l0 = rbase & 1023;
                size_t bh = (size_t)(bb * H_ + h);
                if (part == 0) {
                    float qs = qscale[d];
                    #pragma unroll
                    for (int reg = 0; reg < 4; reg++)
                        Qb[(bh * L_ + l0 + reg) * DH + d] = f2b((v[reg] + bv) * qs);
                } else if (part == 1) {
                    #pragma unroll
                    for (int reg = 0; reg < 4; reg++)
                        Kb[(bh * L_ + l0 + reg) * DH + d] = f2b(v[reg] + bv);
                } else {
                    ushort4 pk;
                    pk.x = f2b(v[0] + bv); pk.y = f2b(v[1] + bv);
                    pk.z = f2b(v[2] + bv); pk.w = f2b(v[3] + bv);
                    *(ushort4*)(Vtb + (bh * DH + d) * L_ + l0) = pk;
                }
            }
        }
    }
}

// ---------------- MFMA flash attention, 32x32x16 (QB=32 per wave) ----------
// (unchanged from verified round 11)
__global__ __launch_bounds__(256, 4) void attn_mfma(
    const u16* __restrict__ Q, const u16* __restrict__ K,
    const u16* __restrict__ Vt, const unsigned char* __restrict__ mask,
    u16* __restrict__ O)
{
    __shared__ u16 Kbuf[2][2048];              // 2 x 4KB (256 slots x 16B)
    __shared__ u16 Vbuf[2][2048];              // 2 x 4KB
    __shared__ u16 P_lds[4][32][36];           // per-wave 32x32 P + pad

    const int bid = blockIdx.x;                // 0..1023
    const int w = (bid & 7) * 128 + (bid >> 3);  // XCD-bijective swizzle
    const int bh = w >> 3;                     // 0..127
    const int blk = w & 7;                     // 0..7 within bh
    const int tid = threadIdx.x;
    const int wid = tid >> 6;
    const int q0 = blk * 128 + wid * 32;       // wave's q base
    const int b = bh >> 3;
    const int h = bh & (H_ - 1);

    const int lane = tid & 63;
    const int c = lane & 31;                   // MFMA32 column
    const int hi = lane >> 5;

    const u16* Qp = Q + ((size_t)bh * L_ + q0) * DH;
    const u16* Kp = K + (size_t)bh * L_ * DH;
    const u16* Vp = Vt + (size_t)bh * DH * L_;
    const unsigned char* mp = mask + (size_t)b * L_;

    // staging map: thread covers slot tid; inverse-swizzled global chunk
    const int krow = tid >> 3, kch = (tid & 7) ^ (krow & 7);
    const int vrow = tid >> 2, vch = (tid & 3) ^ ((vrow & 3) ^ ((vrow >> 2) & 3));
    const u16* Kg = Kp + (size_t)krow * DH + kch * 8;   // + kt*DH per tile
    const u16* Vg = Vp + (size_t)vrow * L_ + vch * 8;   // + kt per tile

    auto stage = [&](int nbuf, int kt) {
        __builtin_amdgcn_global_load_lds(
            (const __attribute__((address_space(1))) unsigned int*)(Kg + (size_t)kt * DH),
            (__attribute__((address_space(3))) unsigned int*)&Kbuf[nbuf][wid * 512],
            16, 0, 0);
        __builtin_amdgcn_global_load_lds(
            (const __attribute__((address_space(1))) unsigned int*)(Vg + kt),
            (__attribute__((address_space(3))) unsigned int*)&Vbuf[nbuf][wid * 512],
            16, 0, 0);
    };

    // whole-row mask presence check (hoisted; mask is usually all-false)
    unsigned int mor = 0;
    {
        const unsigned int* mp32 = (const unsigned int*)mp;
        #pragma unroll
        for (int i = 0; i < 4; i++) mor |= mp32[lane + i * 64];
    }
    const bool anyMask = (__ballot(mor != 0) != 0ULL);

    stage(0, 0);                               // prefetch tile 0

    // Q B-fragments: B[k=d][col=q=c] = Q[c][d], d = s2*16 + hi*8 + j
    bf16x8 qf[4];
    #pragma unroll
    for (int s2 = 0; s2 < 4; s2++)
        qf[s2] = *(const bf16x8*)(Qp + c * DH + s2 * 16 + hi * 8);

    f32x16 oacc0 = {}, oacc1 = {};
    float mrun = -INFINITY, lrun = 0.f;

    // read-side swizzled LDS offsets (u16 indices)
    int kslot[4];
    #pragma unroll
    for (int s2 = 0; s2 < 4; s2++)
        kslot[s2] = (c * 8 + (((2 * s2 + hi)) ^ (c & 7))) * 8;
    const int swzv = (c & 3) ^ ((c >> 2) & 3);
    int vslot[2][2];
    #pragma unroll
    for (int dt = 0; dt < 2; dt++)
        #pragma unroll
        for (int s = 0; s < 2; s++)
            vslot[dt][s] = ((dt * 32 + c) * 4 + (((2 * s + hi)) ^ swzv)) * 8;

    #pragma unroll 1
    for (int t = 0; t < 32; ++t) {
        const int cur = t & 1;
        const int kt = t * 32;
        // retire this wave's own staging DMA before the barrier (race fix)
        asm volatile("s_waitcnt vmcnt(0) lgkmcnt(0)" ::: "memory");
        __syncthreads();

        bf16x8 kf[4];
        #pragma unroll
        for (int s2 = 0; s2 < 4; s2++)
            kf[s2] = *(const bf16x8*)&Kbuf[cur][kslot[s2]];
        bf16x8 vf[2][2];
        #pragma unroll
        for (int dt = 0; dt < 2; dt++)
            #pragma unroll
            for (int s = 0; s < 2; s++)
                vf[dt][s] = *(const bf16x8*)&Vbuf[cur][vslot[dt][s]];

        if (t < 31) stage(cur ^ 1, kt + 32);   // prefetch next tile

        // S^T = K @ Q^T : lane holds S^T[key=(r&3)+8*(r>>2)+4*hi][q=c]
        f32x16 st = {};
        #pragma unroll
        for (int s2 = 0; s2 < 4; s2++)
            st = MFMA32(kf[s2], qf[s2], st);

        if (anyMask) {
            #pragma unroll
            for (int r = 0; r < 16; r++) {
                int key = kt + (r & 3) + 8 * (r >> 2) + 4 * hi;
                if (mp[key]) st[r] = -1e9f;
            }
        }

        // tile max (balanced tree) + cross-half combine
        float m01 = fmaxf(st[0], st[1]),  m23 = fmaxf(st[2], st[3]);
        float m45 = fmaxf(st[4], st[5]),  m67 = fmaxf(st[6], st[7]);
        float m89 = fmaxf(st[8], st[9]),  mab = fmaxf(st[10], st[11]);
        float mcd = fmaxf(st[12], st[13]), mef = fmaxf(st[14], st[15]);
        float tm = fmaxf(fmaxf(fmaxf(m01, m23), fmaxf(m45, m67)),
                         fmaxf(fmaxf(m89, mab), fmaxf(mcd, mef)));
        tm = fmaxf(tm, __shfl_xor(tm, 32));

        if (!__all(tm <= mrun + 8.f)) {        // defer-max rescale (rare)
            float mnew = fmaxf(mrun, tm);
            float corr = EXP2(mrun - mnew);    // col space (q=c)
            lrun *= corr;
            #pragma unroll
            for (int r = 0; r < 16; r++) {
                int row = (r & 3) + 8 * (r >> 2) + 4 * hi;
                float cr = __shfl(corr, row);
                oacc0[r] *= cr;
                oacc1[r] *= cr;
            }
            mrun = mnew;
        }

        // p = exp2(st - mrun); sum in col space (balanced tree)
        float p[16];
        #pragma unroll
        for (int r = 0; r < 16; r++) p[r] = EXP2(st[r] - mrun);
        float s01 = (p[0] + p[1]) + (p[2] + p[3]);
        float s23 = (p[4] + p[5]) + (p[6] + p[7]);
        float s45 = (p[8] + p[9]) + (p[10] + p[11]);
        float s67 = (p[12] + p[13]) + (p[14] + p[15]);
        float ls = (s01 + s23) + (s45 + s67);
        ls += __shfl_xor(ls, 32);
        lrun += ls;

        // P^T -> per-wave LDS [q][key] via hw packed cvt
        #pragma unroll
        for (int rp = 0; rp < 4; rp++) {
            uint2 pw;
            pw.x = cvt_pk_bf16(p[4 * rp], p[4 * rp + 1]);
            pw.y = cvt_pk_bf16(p[4 * rp + 2], p[4 * rp + 3]);
            *(uint2*)(&P_lds[wid][c][8 * rp + 4 * hi]) = pw;
        }
        asm volatile("s_waitcnt lgkmcnt(0)" ::: "memory");
        __builtin_amdgcn_sched_barrier(0);
        // PV A-frags: A[row=q=c][key = s*16 + hi*8 + j]
        bf16x8 pa0 = *(const bf16x8*)(&P_lds[wid][c][hi * 8]);
        bf16x8 pa1 = *(const bf16x8*)(&P_lds[wid][c][16 + hi * 8]);
        asm volatile("" ::: "memory");

        oacc0 = MFMA32(pa0, vf[0][0], oacc0);
        oacc0 = MFMA32(pa1, vf[0][1], oacc0);
        oacc1 = MFMA32(pa0, vf[1][0], oacc1);
        oacc1 = MFMA32(pa1, vf[1][1], oacc1);
        // oacc: lane holds O[q=(r&3)+8*(r>>2)+4*hi][d = dt*32 + c]
    }

    #pragma unroll
    for (int r = 0; r < 16; r++) {
        int row = (r & 3) + 8 * (r >> 2) + 4 * hi;
        float lq = __shfl(lrun, row);
        float inv = 1.f / lq;
        size_t base = ((size_t)(b * L_ + q0 + row)) * E_ + h * DH + c;
        O[base] = f2b(oacc0[r] * inv);
        O[base + 32] = f2b(oacc1[r] * inv);
    }
}

// ---------------- host launch ----------------
extern "C" void kernel_launch(void* const* d_in, const int* in_sizes, int n_in,
                              void* d_out, int out_size, void* d_ws, size_t ws_size,
                              hipStream_t stream) {
    const float* x     = (const float*)d_in[0];
    const float* w_in  = (const float*)d_in[1];
    const float* b_in  = (const float*)d_in[2];
    const float* w_out = (const float*)d_in[3];
    const float* b_out = (const float*)d_in[4];
    const float* qs    = (const float*)d_in[5];
    const unsigned char* mask = (const unsigned char*)d_in[6];
    float* out = (float*)d_out;

    char* base = (char*)d_ws;
    const size_t NELEM = (size_t)B_ * L_ * E_;   // 8388608
    float* qscale = (float*)base;                // 256 B
    u16* xb  = (u16*)(base + 256);
    u16* wib = xb + NELEM;                       // 786432
    u16* wob = wib + 786432;                     // 262144
    u16* Qb  = wob + 262144;
    u16* Kb  = Qb + NELEM;
    u16* Vtb = Kb + NELEM;
    u16* Ob  = Vtb + NELEM;

    qscale_kernel<<<1, 64, 0, stream>>>(qs, qscale);
    cvt_bf16<<<4608, 256, 0, stream>>>(x, w_in, w_out, xb, wib, wob);
    gemm_bf16<0><<<dim3(128, 12), 256, 0, stream>>>(
        xb, wib, b_in, qscale, nullptr, Qb, Kb, Vtb);
    attn_mfma<<<dim3(1024), 256, 0, stream>>>(Qb, Kb, Vtb, mask, Ob);
    gemm_bf16<1><<<dim3(128, 4), 256, 0, stream>>>(
        Ob, wob, b_out, nullptr, out, nullptr, nullptr, nullptr);
}

// Round 13
// 126.033 us; speedup vs baseline: 1.0348x; 1.0348x over previous
//
#include <hip/hip_runtime.h>
#include <hip/hip_bf16.h>
#include <math.h>

// Problem constants (fixed by setup_inputs)
#define B_ 16
#define L_ 1024
#define E_ 512
#define H_ 8
#define DH 64

typedef unsigned short u16;
typedef __attribute__((ext_vector_type(8))) short bf16x8;
typedef __attribute__((ext_vector_type(8))) unsigned short u16x8;
typedef __attribute__((ext_vector_type(4))) float f32x4;
typedef __attribute__((ext_vector_type(16))) float f32x16;

#define MFMA16(A, B, C) __builtin_amdgcn_mfma_f32_16x16x32_bf16(A, B, C, 0, 0, 0)
#define MFMA32(A, B, C) __builtin_amdgcn_mfma_f32_32x32x16_bf16(A, B, C, 0, 0, 0)

#if __has_builtin(__builtin_amdgcn_exp2f)
#define EXP2(x) __builtin_amdgcn_exp2f(x)
#else
#define EXP2(x) exp2f(x)
#endif

__device__ inline u16 f2b(float x) {
    __hip_bfloat16 h = __float2bfloat16(x);
    u16 u; __builtin_memcpy(&u, &h, 2); return u;
}

// hardware packed f32->bf16 (RNE), lo = a, hi = b
__device__ inline unsigned int cvt_pk_bf16(float a, float b) {
    unsigned int r;
    asm("v_cvt_pk_bf16_f32 %0, %1, %2" : "=v"(r) : "v"(a), "v"(b));
    return r;
}

// ---------------- fp32 -> bf16 conversion + QueryScaler fold ----------------
// Block 0 / threads 0..63 additionally compute
// qscale[d] = R_softplus0 * softplus(s) * (1/sqrt(Dh)) * log2(e).
__global__ __launch_bounds__(256) void cvt_bf16(
    const float* __restrict__ x, const float* __restrict__ wi,
    const float* __restrict__ wo, const float* __restrict__ qs_scale,
    u16* __restrict__ xb, u16* __restrict__ wib, u16* __restrict__ wob,
    float* __restrict__ qscale)
{
    if (blockIdx.x == 0 && threadIdx.x < DH) {
        float s = qs_scale[threadIdx.x];
        float sp = (s > 20.f) ? s : log1pf(expf(s));
        qscale[threadIdx.x] = 1.442695041f * sp * 0.125f * 1.442695041f;
    }
    int i = blockIdx.x * 256 + threadIdx.x;
    const float* src; u16* dst; size_t off;
    if (i < 1048576)      { src = x;  dst = xb;  off = (size_t)i * 8; }
    else if (i < 1146880) { src = wi; dst = wib; off = (size_t)(i - 1048576) * 8; }
    else                  { src = wo; dst = wob; off = (size_t)(i - 1146880) * 8; }
    float4 a = *(const float4*)(src + off);
    float4 b = *(const float4*)(src + off + 4);
    u16x8 r;
    r[0] = f2b(a.x); r[1] = f2b(a.y); r[2] = f2b(a.z); r[3] = f2b(a.w);
    r[4] = f2b(b.x); r[5] = f2b(b.y); r[6] = f2b(b.z); r[7] = f2b(b.w);
    *(u16x8*)(dst + off) = r;
}

// ---------------- bf16 MFMA GEMM: C = A(M,512) @ W(N,512)^T + bias --------
// (round-12 structure, verified; perf-neutral vs reg-staged but kept)
template<int MODE>
__global__ __launch_bounds__(256) void gemm_bf16(
    const u16* __restrict__ A, const u16* __restrict__ W,
    const float* __restrict__ bias, const float* __restrict__ qscale,
    float* __restrict__ Dout, u16* __restrict__ Qb, u16* __restrict__ Kb,
    u16* __restrict__ Vtb)
{
    __shared__ u16 sA[2][4096];                // 2 x 8KB (512 slots x 16B)
    __shared__ u16 sB[2][4096];
    const int tid = threadIdx.x;
    const int m0 = blockIdx.x * 128;
    const int n0 = blockIdx.y * 128;
    const int wid = tid >> 6, lane = tid & 63;
    const int g = lane >> 4, c = lane & 15;
    const int wr = wid >> 1, wc = wid & 1;

    const int arow = tid >> 2;
    const int swg = (arow & 3) ^ ((arow >> 2) & 3);
    const int ch = (tid & 3) ^ swg;
    const u16* Asrc = A + (size_t)(m0 + arow) * 512 + ch * 8;
    const u16* Bsrc = W + (size_t)(n0 + arow) * 512 + ch * 8;

    auto stage = [&](int nbuf, int ks) {
        const int k0 = ks * 32;
        __builtin_amdgcn_global_load_lds(
            (const __attribute__((address_space(1))) unsigned int*)(Asrc + k0),
            (__attribute__((address_space(3))) unsigned int*)&sA[nbuf][wid * 512], 16, 0, 0);
        __builtin_amdgcn_global_load_lds(
            (const __attribute__((address_space(1))) unsigned int*)(Asrc + (size_t)64 * 512 + k0),
            (__attribute__((address_space(3))) unsigned int*)&sA[nbuf][2048 + wid * 512], 16, 0, 0);
        __builtin_amdgcn_global_load_lds(
            (const __attribute__((address_space(1))) unsigned int*)(Bsrc + k0),
            (__attribute__((address_space(3))) unsigned int*)&sB[nbuf][wid * 512], 16, 0, 0);
        __builtin_amdgcn_global_load_lds(
            (const __attribute__((address_space(1))) unsigned int*)(Bsrc + (size_t)64 * 512 + k0),
            (__attribute__((address_space(3))) unsigned int*)&sB[nbuf][2048 + wid * 512], 16, 0, 0);
    };

    f32x4 acc[4][4];
    #pragma unroll
    for (int m = 0; m < 4; m++)
        #pragma unroll
        for (int n = 0; n < 4; n++) acc[m][n] = (f32x4){0.f, 0.f, 0.f, 0.f};

    const int swr = (c & 3) ^ ((c >> 2) & 3);
    const int chA = (g ^ swr) * 8;

    stage(0, 0);
    #pragma unroll 1
    for (int ks = 0; ks < 16; ks++) {
        const int cur = ks & 1;
        asm volatile("s_waitcnt vmcnt(0) lgkmcnt(0)" ::: "memory");
        __syncthreads();
        if (ks < 15) stage(cur ^ 1, ks + 1);   // overlaps with MFMA below

        bf16x8 af[4], bfr[4];
        #pragma unroll
        for (int m = 0; m < 4; m++)
            af[m] = *(const bf16x8*)&sA[cur][(wr * 64 + m * 16 + c) * 32 + chA];
        #pragma unroll
        for (int n = 0; n < 4; n++)
            bfr[n] = *(const bf16x8*)&sB[cur][(wc * 64 + n * 16 + c) * 32 + chA];
        #pragma unroll
        for (int m = 0; m < 4; m++)
            #pragma unroll
            for (int n = 0; n < 4; n++)
                acc[m][n] = MFMA16(af[m], bfr[n], acc[m][n]);
    }

    #pragma unroll
    for (int m = 0; m < 4; m++) {
        int rbase = m0 + wr * 64 + m * 16 + 4 * g;
        #pragma unroll
        for (int n = 0; n < 4; n++) {
            int f = n0 + wc * 64 + n * 16 + c;
            f32x4 v = acc[m][n];
            float bv = bias[f];
            if (MODE == 1) {
                #pragma unroll
                for (int reg = 0; reg < 4; reg++)
                    Dout[(size_t)(rbase + reg) * E_ + f] = v[reg] + bv;
            } else {
                int part = f >> 9, w = f & 511, h = w >> 6, d = w & 63;
                int bb = rbase >> 10;
                int l0 = rbase & 1023;
                size_t bh = (size_t)(bb * H_ + h);
                if (part == 0) {
                    float qs = qscale[d];
                    #pragma unroll
                    for (int reg = 0; reg < 4; reg++)
                        Qb[(bh * L_ + l0 + reg) * DH + d] = f2b((v[reg] + bv) * qs);
                } else if (part == 1) {
                    #pragma unroll
                    for (int reg = 0; reg < 4; reg++)
                        Kb[(bh * L_ + l0 + reg) * DH + d] = f2b(v[reg] + bv);
                } else {
                    ushort4 pk;
                    pk.x = f2b(v[0] + bv); pk.y = f2b(v[1] + bv);
                    pk.z = f2b(v[2] + bv); pk.w = f2b(v[3] + bv);
                    *(ushort4*)(Vtb + (bh * DH + d) * L_ + l0) = pk;
                }
            }
        }
    }
}

// ---------------- MFMA flash attention, 32x32x16, counted-vmcnt pipeline ---
// Round-13 change: triple-buffered K/V staging, prefetch depth 2, RAW
// s_barrier with COUNTED vmcnt (T3/T4): before the barrier of tile t each
// wave waits vmcnt(2) — its stage(t) DMAs (older than the in-flight
// stage(t+1)) are retired — never vmcnt(0) in the main loop, so one stage
// stays in flight across the barrier. FIFO audit: outstanding at the wait
// are stages t,t+1 (4 DMAs) [+ possibly mask loads, which are NEWER and
// thus occupy the 2-newest slots without weakening the guarantee].
// Tail t=31 drains vmcnt(0). Everything else identical to round 11/12.
__global__ __launch_bounds__(256, 4) void attn_mfma(
    const u16* __restrict__ Q, const u16* __restrict__ K,
    const u16* __restrict__ Vt, const unsigned char* __restrict__ mask,
    u16* __restrict__ O)
{
    __shared__ u16 Kbuf[3][2048];              // 3 x 4KB (256 slots x 16B)
    __shared__ u16 Vbuf[3][2048];              // 3 x 4KB
    __shared__ u16 P_lds[4][32][36];           // per-wave 32x32 P + pad

    const int bid = blockIdx.x;                // 0..1023
    const int w = (bid & 7) * 128 + (bid >> 3);  // XCD-bijective swizzle
    const int bh = w >> 3;                     // 0..127
    const int blk = w & 7;                     // 0..7 within bh
    const int tid = threadIdx.x;
    const int wid = tid >> 6;
    const int q0 = blk * 128 + wid * 32;       // wave's q base
    const int b = bh >> 3;
    const int h = bh & (H_ - 1);

    const int lane = tid & 63;
    const int c = lane & 31;                   // MFMA32 column
    const int hi = lane >> 5;

    const u16* Qp = Q + ((size_t)bh * L_ + q0) * DH;
    const u16* Kp = K + (size_t)bh * L_ * DH;
    const u16* Vp = Vt + (size_t)bh * DH * L_;
    const unsigned char* mp = mask + (size_t)b * L_;

    // staging map: thread covers slot tid; inverse-swizzled global chunk
    const int krow = tid >> 3, kch = (tid & 7) ^ (krow & 7);
    const int vrow = tid >> 2, vch = (tid & 3) ^ ((vrow & 3) ^ ((vrow >> 2) & 3));
    const u16* Kg = Kp + (size_t)krow * DH + kch * 8;   // + kt*DH per tile
    const u16* Vg = Vp + (size_t)vrow * L_ + vch * 8;   // + kt per tile

    auto stage = [&](int nbuf, int kt) {
        __builtin_amdgcn_global_load_lds(
            (const __attribute__((address_space(1))) unsigned int*)(Kg + (size_t)kt * DH),
            (__attribute__((address_space(3))) unsigned int*)&Kbuf[nbuf][wid * 512],
            16, 0, 0);
        __builtin_amdgcn_global_load_lds(
            (const __attribute__((address_space(1))) unsigned int*)(Vg + kt),
            (__attribute__((address_space(3))) unsigned int*)&Vbuf[nbuf][wid * 512],
            16, 0, 0);
    };

    // whole-row mask presence check + Q fragments (issued BEFORE the stages
    // so the counted vmcnt's "oldest retired" audit stays simple)
    unsigned int mor = 0;
    {
        const unsigned int* mp32 = (const unsigned int*)mp;
        #pragma unroll
        for (int i = 0; i < 4; i++) mor |= mp32[lane + i * 64];
    }
    const bool anyMask = (__ballot(mor != 0) != 0ULL);

    bf16x8 qf[4];
    #pragma unroll
    for (int s2 = 0; s2 < 4; s2++)
        qf[s2] = *(const bf16x8*)(Qp + c * DH + s2 * 16 + hi * 8);

    stage(0, 0);                               // prefetch tiles 0,1
    stage(1, 32);

    f32x16 oacc0 = {}, oacc1 = {};
    float mrun = -INFINITY, lrun = 0.f;

    // read-side swizzled LDS offsets (u16 indices)
    int kslot[4];
    #pragma unroll
    for (int s2 = 0; s2 < 4; s2++)
        kslot[s2] = (c * 8 + (((2 * s2 + hi)) ^ (c & 7))) * 8;
    const int swzv = (c & 3) ^ ((c >> 2) & 3);
    int vslot[2][2];
    #pragma unroll
    for (int dt = 0; dt < 2; dt++)
        #pragma unroll
        for (int s = 0; s < 2; s++)
            vslot[dt][s] = ((dt * 32 + c) * 4 + (((2 * s + hi)) ^ swzv)) * 8;

    #pragma unroll 1
    for (int t = 0; t < 32; ++t) {
        const int cur = t % 3;
        const int kt = t * 32;
        // counted wait: stage(t) retired (2 newest = stage(t+1) may fly)
        if (t < 31) { asm volatile("s_waitcnt vmcnt(2) lgkmcnt(0)" ::: "memory"); }
        else        { asm volatile("s_waitcnt vmcnt(0) lgkmcnt(0)" ::: "memory"); }
        __builtin_amdgcn_s_barrier();
        asm volatile("" ::: "memory");

        bf16x8 kf[4];
        #pragma unroll
        for (int s2 = 0; s2 < 4; s2++)
            kf[s2] = *(const bf16x8*)&Kbuf[cur][kslot[s2]];
        bf16x8 vf[2][2];
        #pragma unroll
        for (int dt = 0; dt < 2; dt++)
            #pragma unroll
            for (int s = 0; s < 2; s++)
                vf[dt][s] = *(const bf16x8*)&Vbuf[cur][vslot[dt][s]];

        if (t < 30) stage((t + 2) % 3, kt + 64);   // keep depth-2 in flight

        // S^T = K @ Q^T : lane holds S^T[key=(r&3)+8*(r>>2)+4*hi][q=c]
        f32x16 st = {};
        #pragma unroll
        for (int s2 = 0; s2 < 4; s2++)
            st = MFMA32(kf[s2], qf[s2], st);

        if (anyMask) {
            #pragma unroll
            for (int r = 0; r < 16; r++) {
                int key = kt + (r & 3) + 8 * (r >> 2) + 4 * hi;
                if (mp[key]) st[r] = -1e9f;
            }
        }

        // tile max (balanced tree) + cross-half combine
        float m01 = fmaxf(st[0], st[1]),  m23 = fmaxf(st[2], st[3]);
        float m45 = fmaxf(st[4], st[5]),  m67 = fmaxf(st[6], st[7]);
        float m89 = fmaxf(st[8], st[9]),  mab = fmaxf(st[10], st[11]);
        float mcd = fmaxf(st[12], st[13]), mef = fmaxf(st[14], st[15]);
        float tm = fmaxf(fmaxf(fmaxf(m01, m23), fmaxf(m45, m67)),
                         fmaxf(fmaxf(m89, mab), fmaxf(mcd, mef)));
        tm = fmaxf(tm, __shfl_xor(tm, 32));

        if (!__all(tm <= mrun + 8.f)) {        // defer-max rescale (rare)
            float mnew = fmaxf(mrun, tm);
            float corr = EXP2(mrun - mnew);    // col space (q=c)
            lrun *= corr;
            #pragma unroll
            for (int r = 0; r < 16; r++) {
                int row = (r & 3) + 8 * (r >> 2) + 4 * hi;
                float cr = __shfl(corr, row);
                oacc0[r] *= cr;
                oacc1[r] *= cr;
            }
            mrun = mnew;
        }

        // p = exp2(st - mrun); sum in col space (balanced tree)
        float p[16];
        #pragma unroll
        for (int r = 0; r < 16; r++) p[r] = EXP2(st[r] - mrun);
        float s01 = (p[0] + p[1]) + (p[2] + p[3]);
        float s23 = (p[4] + p[5]) + (p[6] + p[7]);
        float s45 = (p[8] + p[9]) + (p[10] + p[11]);
        float s67 = (p[12] + p[13]) + (p[14] + p[15]);
        float ls = (s01 + s23) + (s45 + s67);
        ls += __shfl_xor(ls, 32);
        lrun += ls;

        // P^T -> per-wave LDS [q][key] via hw packed cvt
        #pragma unroll
        for (int rp = 0; rp < 4; rp++) {
            uint2 pw;
            pw.x = cvt_pk_bf16(p[4 * rp], p[4 * rp + 1]);
            pw.y = cvt_pk_bf16(p[4 * rp + 2], p[4 * rp + 3]);
            *(uint2*)(&P_lds[wid][c][8 * rp + 4 * hi]) = pw;
        }
        asm volatile("s_waitcnt lgkmcnt(0)" ::: "memory");
        __builtin_amdgcn_sched_barrier(0);
        // PV A-frags: A[row=q=c][key = s*16 + hi*8 + j]
        bf16x8 pa0 = *(const bf16x8*)(&P_lds[wid][c][hi * 8]);
        bf16x8 pa1 = *(const bf16x8*)(&P_lds[wid][c][16 + hi * 8]);
        asm volatile("" ::: "memory");

        oacc0 = MFMA32(pa0, vf[0][0], oacc0);
        oacc0 = MFMA32(pa1, vf[0][1], oacc0);
        oacc1 = MFMA32(pa0, vf[1][0], oacc1);
        oacc1 = MFMA32(pa1, vf[1][1], oacc1);
        // oacc: lane holds O[q=(r&3)+8*(r>>2)+4*hi][d = dt*32 + c]
    }

    #pragma unroll
    for (int r = 0; r < 16; r++) {
        int row = (r & 3) + 8 * (r >> 2) + 4 * hi;
        float lq = __shfl(lrun, row);
        float inv = 1.f / lq;
        size_t base = ((size_t)(b * L_ + q0 + row)) * E_ + h * DH + c;
        O[base] = f2b(oacc0[r] * inv);
        O[base + 32] = f2b(oacc1[r] * inv);
    }
}

// ---------------- host launch ----------------
extern "C" void kernel_launch(void* const* d_in, const int* in_sizes, int n_in,
                              void* d_out, int out_size, void* d_ws, size_t ws_size,
                              hipStream_t stream) {
    const float* x     = (const float*)d_in[0];
    const float* w_in  = (const float*)d_in[1];
    const float* b_in  = (const float*)d_in[2];
    const float* w_out = (const float*)d_in[3];
    const float* b_out = (const float*)d_in[4];
    const float* qs    = (const float*)d_in[5];
    const unsigned char* mask = (const unsigned char*)d_in[6];
    float* out = (float*)d_out;

    char* base = (char*)d_ws;
    const size_t NELEM = (size_t)B_ * L_ * E_;   // 8388608
    float* qscale = (float*)base;                // 256 B
    u16* xb  = (u16*)(base + 256);
    u16* wib = xb + NELEM;                       // 786432
    u16* wob = wib + 786432;                     // 262144
    u16* Qb  = wob + 262144;
    u16* Kb  = Qb + NELEM;
    u16* Vtb = Kb + NELEM;
    u16* Ob  = Vtb + NELEM;

    cvt_bf16<<<4608, 256, 0, stream>>>(x, w_in, w_out, qs, xb, wib, wob, qscale);
    gemm_bf16<0><<<dim3(128, 12), 256, 0, stream>>>(
        xb, wib, b_in, qscale, nullptr, Qb, Kb, Vtb);
    attn_mfma<<<dim3(1024), 256, 0, stream>>>(Qb, Kb, Vtb, mask, Ob);
    gemm_bf16<1><<<dim3(128, 4), 256, 0, stream>>>(
        Ob, wob, b_out, nullptr, out, nullptr, nullptr, nullptr);
}

// Round 14
// 123.593 us; speedup vs baseline: 1.0553x; 1.0197x over previous
//
#include <hip/hip_runtime.h>
#include <hip/hip_bf16.h>
#include <math.h>

// Problem constants (fixed by setup_inputs)
#define B_ 16
#define L_ 1024
#define E_ 512
#define H_ 8
#define DH 64

typedef unsigned short u16;
typedef __attribute__((ext_vector_type(8))) short bf16x8;
typedef __attribute__((ext_vector_type(8))) unsigned short u16x8;
typedef __attribute__((ext_vector_type(4))) float f32x4;
typedef __attribute__((ext_vector_type(16))) float f32x16;

#define MFMA16(A, B, C) __builtin_amdgcn_mfma_f32_16x16x32_bf16(A, B, C, 0, 0, 0)
#define MFMA32(A, B, C) __builtin_amdgcn_mfma_f32_32x32x16_bf16(A, B, C, 0, 0, 0)

#if __has_builtin(__builtin_amdgcn_exp2f)
#define EXP2(x) __builtin_amdgcn_exp2f(x)
#else
#define EXP2(x) exp2f(x)
#endif

__device__ inline u16 f2b(float x) {
    __hip_bfloat16 h = __float2bfloat16(x);
    u16 u; __builtin_memcpy(&u, &h, 2); return u;
}

// hardware packed f32->bf16 (RNE), lo = a, hi = b
__device__ inline unsigned int cvt_pk_bf16(float a, float b) {
    unsigned int r;
    asm("v_cvt_pk_bf16_f32 %0, %1, %2" : "=v"(r) : "v"(a), "v"(b));
    return r;
}

// ---------------- fp32 -> bf16 conversion + QueryScaler fold ----------------
__global__ __launch_bounds__(256) void cvt_bf16(
    const float* __restrict__ x, const float* __restrict__ wi,
    const float* __restrict__ wo, const float* __restrict__ qs_scale,
    u16* __restrict__ xb, u16* __restrict__ wib, u16* __restrict__ wob,
    float* __restrict__ qscale)
{
    if (blockIdx.x == 0 && threadIdx.x < DH) {
        float s = qs_scale[threadIdx.x];
        float sp = (s > 20.f) ? s : log1pf(expf(s));
        qscale[threadIdx.x] = 1.442695041f * sp * 0.125f * 1.442695041f;
    }
    int i = blockIdx.x * 256 + threadIdx.x;
    const float* src; u16* dst; size_t off;
    if (i < 1048576)      { src = x;  dst = xb;  off = (size_t)i * 8; }
    else if (i < 1146880) { src = wi; dst = wib; off = (size_t)(i - 1048576) * 8; }
    else                  { src = wo; dst = wob; off = (size_t)(i - 1146880) * 8; }
    float4 a = *(const float4*)(src + off);
    float4 b = *(const float4*)(src + off + 4);
    u16x8 r;
    r[0] = f2b(a.x); r[1] = f2b(a.y); r[2] = f2b(a.z); r[3] = f2b(a.w);
    r[4] = f2b(b.x); r[5] = f2b(b.y); r[6] = f2b(b.z); r[7] = f2b(b.w);
    *(u16x8*)(dst + off) = r;
}

// ---------------- bf16 MFMA GEMM: C = A(M,512) @ W(N,512)^T + bias --------
// (round-12 structure, verified)
template<int MODE>
__global__ __launch_bounds__(256) void gemm_bf16(
    const u16* __restrict__ A, const u16* __restrict__ W,
    const float* __restrict__ bias, const float* __restrict__ qscale,
    float* __restrict__ Dout, u16* __restrict__ Qb, u16* __restrict__ Kb,
    u16* __restrict__ Vtb)
{
    __shared__ u16 sA[2][4096];                // 2 x 8KB (512 slots x 16B)
    __shared__ u16 sB[2][4096];
    const int tid = threadIdx.x;
    const int m0 = blockIdx.x * 128;
    const int n0 = blockIdx.y * 128;
    const int wid = tid >> 6, lane = tid & 63;
    const int g = lane >> 4, c = lane & 15;
    const int wr = wid >> 1, wc = wid & 1;

    const int arow = tid >> 2;
    const int swg = (arow & 3) ^ ((arow >> 2) & 3);
    const int ch = (tid & 3) ^ swg;
    const u16* Asrc = A + (size_t)(m0 + arow) * 512 + ch * 8;
    const u16* Bsrc = W + (size_t)(n0 + arow) * 512 + ch * 8;

    auto stage = [&](int nbuf, int ks) {
        const int k0 = ks * 32;
        __builtin_amdgcn_global_load_lds(
            (const __attribute__((address_space(1))) unsigned int*)(Asrc + k0),
            (__attribute__((address_space(3))) unsigned int*)&sA[nbuf][wid * 512], 16, 0, 0);
        __builtin_amdgcn_global_load_lds(
            (const __attribute__((address_space(1))) unsigned int*)(Asrc + (size_t)64 * 512 + k0),
            (__attribute__((address_space(3))) unsigned int*)&sA[nbuf][2048 + wid * 512], 16, 0, 0);
        __builtin_amdgcn_global_load_lds(
            (const __attribute__((address_space(1))) unsigned int*)(Bsrc + k0),
            (__attribute__((address_space(3))) unsigned int*)&sB[nbuf][wid * 512], 16, 0, 0);
        __builtin_amdgcn_global_load_lds(
            (const __attribute__((address_space(1))) unsigned int*)(Bsrc + (size_t)64 * 512 + k0),
            (__attribute__((address_space(3))) unsigned int*)&sB[nbuf][2048 + wid * 512], 16, 0, 0);
    };

    f32x4 acc[4][4];
    #pragma unroll
    for (int m = 0; m < 4; m++)
        #pragma unroll
        for (int n = 0; n < 4; n++) acc[m][n] = (f32x4){0.f, 0.f, 0.f, 0.f};

    const int swr = (c & 3) ^ ((c >> 2) & 3);
    const int chA = (g ^ swr) * 8;

    stage(0, 0);
    #pragma unroll 1
    for (int ks = 0; ks < 16; ks++) {
        const int cur = ks & 1;
        asm volatile("s_waitcnt vmcnt(0) lgkmcnt(0)" ::: "memory");
        __syncthreads();
        if (ks < 15) stage(cur ^ 1, ks + 1);   // overlaps with MFMA below

        bf16x8 af[4], bfr[4];
        #pragma unroll
        for (int m = 0; m < 4; m++)
            af[m] = *(const bf16x8*)&sA[cur][(wr * 64 + m * 16 + c) * 32 + chA];
        #pragma unroll
        for (int n = 0; n < 4; n++)
            bfr[n] = *(const bf16x8*)&sB[cur][(wc * 64 + n * 16 + c) * 32 + chA];
        #pragma unroll
        for (int m = 0; m < 4; m++)
            #pragma unroll
            for (int n = 0; n < 4; n++)
                acc[m][n] = MFMA16(af[m], bfr[n], acc[m][n]);
    }

    #pragma unroll
    for (int m = 0; m < 4; m++) {
        int rbase = m0 + wr * 64 + m * 16 + 4 * g;
        #pragma unroll
        for (int n = 0; n < 4; n++) {
            int f = n0 + wc * 64 + n * 16 + c;
            f32x4 v = acc[m][n];
            float bv = bias[f];
            if (MODE == 1) {
                #pragma unroll
                for (int reg = 0; reg < 4; reg++)
                    Dout[(size_t)(rbase + reg) * E_ + f] = v[reg] + bv;
            } else {
                int part = f >> 9, w = f & 511, h = w >> 6, d = w & 63;
                int bb = rbase >> 10;
                int l0 = rbase & 1023;
                size_t bh = (size_t)(bb * H_ + h);
                if (part == 0) {
                    float qs = qscale[d];
                    #pragma unroll
                    for (int reg = 0; reg < 4; reg++)
                        Qb[(bh * L_ + l0 + reg) * DH + d] = f2b((v[reg] + bv) * qs);
                } else if (part == 1) {
                    #pragma unroll
                    for (int reg = 0; reg < 4; reg++)
                        Kb[(bh * L_ + l0 + reg) * DH + d] = f2b(v[reg] + bv);
                } else {
                    ushort4 pk;
                    pk.x = f2b(v[0] + bv); pk.y = f2b(v[1] + bv);
                    pk.z = f2b(v[2] + bv); pk.w = f2b(v[3] + bv);
                    *(ushort4*)(Vtb + (bh * DH + d) * L_ + l0) = pk;
                }
            }
        }
    }
}

// ---------------- MFMA flash attention, 32x32x16, in-register P (T12) ------
// Round-14 change: P^T->PA redistribution done IN REGISTER via
// v_cvt_pk_bf16_f32 + v_permlane32_swap_b32 (replaces the P_lds roundtrip,
// which was the serial ~150cyc/tile chain + the 2.1M bank conflicts).
// Pair algebra (lane(c,hi) holds p[r] = P[q=c][key=(r&3)+8(r>>2)+4hi]):
//   X=cvtpk(p0,p1)=[{k0k1}lo|{k4k5}hi], Y=cvtpk(p4,p5)=[{k8k9}lo|{k12k13}hi]
//   swap X.hi<->Y.lo -> X'=[{k0k1}|{k8k9}]=pa.w0, Y'=[{k4k5}|{k12k13}]=pa.w2
// Two swaps per 16-key half -> pa0/pa1 in 8 cvt_pk + 4 swaps, no LDS.
// Rest identical to verified round-13 (triple-buffer counted-vmcnt staging).
__global__ __launch_bounds__(256, 4) void attn_mfma(
    const u16* __restrict__ Q, const u16* __restrict__ K,
    const u16* __restrict__ Vt, const unsigned char* __restrict__ mask,
    u16* __restrict__ O)
{
    __shared__ u16 Kbuf[3][2048];              // 3 x 4KB (256 slots x 16B)
    __shared__ u16 Vbuf[3][2048];              // 3 x 4KB

    const int bid = blockIdx.x;                // 0..1023
    const int w = (bid & 7) * 128 + (bid >> 3);  // XCD-bijective swizzle
    const int bh = w >> 3;                     // 0..127
    const int blk = w & 7;                     // 0..7 within bh
    const int tid = threadIdx.x;
    const int wid = tid >> 6;
    const int q0 = blk * 128 + wid * 32;       // wave's q base
    const int b = bh >> 3;
    const int h = bh & (H_ - 1);

    const int lane = tid & 63;
    const int c = lane & 31;                   // MFMA32 column
    const int hi = lane >> 5;

    const u16* Qp = Q + ((size_t)bh * L_ + q0) * DH;
    const u16* Kp = K + (size_t)bh * L_ * DH;
    const u16* Vp = Vt + (size_t)bh * DH * L_;
    const unsigned char* mp = mask + (size_t)b * L_;

    // staging map: thread covers slot tid; inverse-swizzled global chunk
    const int krow = tid >> 3, kch = (tid & 7) ^ (krow & 7);
    const int vrow = tid >> 2, vch = (tid & 3) ^ ((vrow & 3) ^ ((vrow >> 2) & 3));
    const u16* Kg = Kp + (size_t)krow * DH + kch * 8;   // + kt*DH per tile
    const u16* Vg = Vp + (size_t)vrow * L_ + vch * 8;   // + kt per tile

    auto stage = [&](int nbuf, int kt) {
        __builtin_amdgcn_global_load_lds(
            (const __attribute__((address_space(1))) unsigned int*)(Kg + (size_t)kt * DH),
            (__attribute__((address_space(3))) unsigned int*)&Kbuf[nbuf][wid * 512],
            16, 0, 0);
        __builtin_amdgcn_global_load_lds(
            (const __attribute__((address_space(1))) unsigned int*)(Vg + kt),
            (__attribute__((address_space(3))) unsigned int*)&Vbuf[nbuf][wid * 512],
            16, 0, 0);
    };

    // mask presence + Q fragments issued BEFORE the stages
    unsigned int mor = 0;
    {
        const unsigned int* mp32 = (const unsigned int*)mp;
        #pragma unroll
        for (int i = 0; i < 4; i++) mor |= mp32[lane + i * 64];
    }
    const bool anyMask = (__ballot(mor != 0) != 0ULL);

    bf16x8 qf[4];
    #pragma unroll
    for (int s2 = 0; s2 < 4; s2++)
        qf[s2] = *(const bf16x8*)(Qp + c * DH + s2 * 16 + hi * 8);

    stage(0, 0);                               // prefetch tiles 0,1
    stage(1, 32);

    f32x16 oacc0 = {}, oacc1 = {};
    float mrun = -INFINITY, lrun = 0.f;

    // read-side swizzled LDS offsets (u16 indices)
    int kslot[4];
    #pragma unroll
    for (int s2 = 0; s2 < 4; s2++)
        kslot[s2] = (c * 8 + (((2 * s2 + hi)) ^ (c & 7))) * 8;
    const int swzv = (c & 3) ^ ((c >> 2) & 3);
    int vslot[2][2];
    #pragma unroll
    for (int dt = 0; dt < 2; dt++)
        #pragma unroll
        for (int s = 0; s < 2; s++)
            vslot[dt][s] = ((dt * 32 + c) * 4 + (((2 * s + hi)) ^ swzv)) * 8;

    #pragma unroll 1
    for (int t = 0; t < 32; ++t) {
        const int cur = t % 3;
        const int kt = t * 32;
        // counted wait: stage(t) retired (2 newest = stage(t+1) may fly)
        if (t < 31) { asm volatile("s_waitcnt vmcnt(2) lgkmcnt(0)" ::: "memory"); }
        else        { asm volatile("s_waitcnt vmcnt(0) lgkmcnt(0)" ::: "memory"); }
        __builtin_amdgcn_s_barrier();
        asm volatile("" ::: "memory");

        bf16x8 kf[4];
        #pragma unroll
        for (int s2 = 0; s2 < 4; s2++)
            kf[s2] = *(const bf16x8*)&Kbuf[cur][kslot[s2]];
        bf16x8 vf[2][2];
        #pragma unroll
        for (int dt = 0; dt < 2; dt++)
            #pragma unroll
            for (int s = 0; s < 2; s++)
                vf[dt][s] = *(const bf16x8*)&Vbuf[cur][vslot[dt][s]];

        if (t < 30) stage((t + 2) % 3, kt + 64);   // keep depth-2 in flight

        // S^T = K @ Q^T : lane holds S^T[key=(r&3)+8*(r>>2)+4*hi][q=c]
        f32x16 st = {};
        #pragma unroll
        for (int s2 = 0; s2 < 4; s2++)
            st = MFMA32(kf[s2], qf[s2], st);

        if (anyMask) {
            #pragma unroll
            for (int r = 0; r < 16; r++) {
                int key = kt + (r & 3) + 8 * (r >> 2) + 4 * hi;
                if (mp[key]) st[r] = -1e9f;
            }
        }

        // tile max (balanced tree) + cross-half combine
        float m01 = fmaxf(st[0], st[1]),  m23 = fmaxf(st[2], st[3]);
        float m45 = fmaxf(st[4], st[5]),  m67 = fmaxf(st[6], st[7]);
        float m89 = fmaxf(st[8], st[9]),  mab = fmaxf(st[10], st[11]);
        float mcd = fmaxf(st[12], st[13]), mef = fmaxf(st[14], st[15]);
        float tm = fmaxf(fmaxf(fmaxf(m01, m23), fmaxf(m45, m67)),
                         fmaxf(fmaxf(m89, mab), fmaxf(mcd, mef)));
        tm = fmaxf(tm, __shfl_xor(tm, 32));

        if (!__all(tm <= mrun + 8.f)) {        // defer-max rescale (rare)
            float mnew = fmaxf(mrun, tm);
            float corr = EXP2(mrun - mnew);    // col space (q=c)
            lrun *= corr;
            #pragma unroll
            for (int r = 0; r < 16; r++) {
                int row = (r & 3) + 8 * (r >> 2) + 4 * hi;
                float cr = __shfl(corr, row);
                oacc0[r] *= cr;
                oacc1[r] *= cr;
            }
            mrun = mnew;
        }

        // p = exp2(st - mrun); sum in col space (balanced tree)
        float p[16];
        #pragma unroll
        for (int r = 0; r < 16; r++) p[r] = EXP2(st[r] - mrun);
        float s01 = (p[0] + p[1]) + (p[2] + p[3]);
        float s23 = (p[4] + p[5]) + (p[6] + p[7]);
        float s45 = (p[8] + p[9]) + (p[10] + p[11]);
        float s67 = (p[12] + p[13]) + (p[14] + p[15]);
        float ls = (s01 + s23) + (s45 + s67);
        ls += __shfl_xor(ls, 32);
        lrun += ls;

        // ---- in-register P redistribution (T12): cvt_pk + permlane32_swap
        unsigned int x0 = cvt_pk_bf16(p[0],  p[1]);
        unsigned int x1 = cvt_pk_bf16(p[2],  p[3]);
        unsigned int y0 = cvt_pk_bf16(p[4],  p[5]);
        unsigned int y1 = cvt_pk_bf16(p[6],  p[7]);
        unsigned int x2 = cvt_pk_bf16(p[8],  p[9]);
        unsigned int x3 = cvt_pk_bf16(p[10], p[11]);
        unsigned int y2 = cvt_pk_bf16(p[12], p[13]);
        unsigned int y3 = cvt_pk_bf16(p[14], p[15]);
        asm volatile("v_permlane32_swap_b32 %0, %1" : "+v"(x0), "+v"(y0));
        asm volatile("v_permlane32_swap_b32 %0, %1" : "+v"(x1), "+v"(y1));
        asm volatile("v_permlane32_swap_b32 %0, %1" : "+v"(x2), "+v"(y2));
        asm volatile("v_permlane32_swap_b32 %0, %1" : "+v"(x3), "+v"(y3));
        union { unsigned int u[4]; bf16x8 v; } pk0u, pk1u;
        pk0u.u[0] = x0; pk0u.u[1] = x1; pk0u.u[2] = y0; pk0u.u[3] = y1;
        pk1u.u[0] = x2; pk1u.u[1] = x3; pk1u.u[2] = y2; pk1u.u[3] = y3;
        bf16x8 pa0 = pk0u.v;                   // A[row=q=c][key=hi*8+j]
        bf16x8 pa1 = pk1u.v;                   // A[row=q=c][key=16+hi*8+j]

        oacc0 = MFMA32(pa0, vf[0][0], oacc0);
        oacc0 = MFMA32(pa1, vf[0][1], oacc0);
        oacc1 = MFMA32(pa0, vf[1][0], oacc1);
        oacc1 = MFMA32(pa1, vf[1][1], oacc1);
        // oacc: lane holds O[q=(r&3)+8*(r>>2)+4*hi][d = dt*32 + c]
    }

    #pragma unroll
    for (int r = 0; r < 16; r++) {
        int row = (r & 3) + 8 * (r >> 2) + 4 * hi;
        float lq = __shfl(lrun, row);
        float inv = 1.f / lq;
        size_t base = ((size_t)(b * L_ + q0 + row)) * E_ + h * DH + c;
        O[base] = f2b(oacc0[r] * inv);
        O[base + 32] = f2b(oacc1[r] * inv);
    }
}

// ---------------- host launch ----------------
extern "C" void kernel_launch(void* const* d_in, const int* in_sizes, int n_in,
                              void* d_out, int out_size, void* d_ws, size_t ws_size,
                              hipStream_t stream) {
    const float* x     = (const float*)d_in[0];
    const float* w_in  = (const float*)d_in[1];
    const float* b_in  = (const float*)d_in[2];
    const float* w_out = (const float*)d_in[3];
    const float* b_out = (const float*)d_in[4];
    const float* qs    = (const float*)d_in[5];
    const unsigned char* mask = (const unsigned char*)d_in[6];
    float* out = (float*)d_out;

    char* base = (char*)d_ws;
    const size_t NELEM = (size_t)B_ * L_ * E_;   // 8388608
    float* qscale = (float*)base;                // 256 B
    u16* xb  = (u16*)(base + 256);
    u16* wib = xb + NELEM;                       // 786432
    u16* wob = wib + 786432;                     // 262144
    u16* Qb  = wob + 262144;
    u16* Kb  = Qb + NELEM;
    u16* Vtb = Kb + NELEM;
    u16* Ob  = Vtb + NELEM;

    cvt_bf16<<<4608, 256, 0, stream>>>(x, w_in, w_out, qs, xb, wib, wob, qscale);
    gemm_bf16<0><<<dim3(128, 12), 256, 0, stream>>>(
        xb, wib, b_in, qscale, nullptr, Qb, Kb, Vtb);
    attn_mfma<<<dim3(1024), 256, 0, stream>>>(Qb, Kb, Vtb, mask, Ob);
    gemm_bf16<1><<<dim3(128, 4), 256, 0, stream>>>(
        Ob, wob, b_out, nullptr, out, nullptr, nullptr, nullptr);
}